// Round 4
// baseline (99.487 us; speedup 1.0000x reference)
//
#include <hip/hip_runtime.h>

#define BETA_F 0.001f
constexpr int Bn = 8192, Dd = 1024, Kk = 2048, Ee = 512;

// ---------------------------------------------------------------------------
// Collapsed pipeline (validated R3-R6, absmax 0.0 every round):
//   m_e  = mean_k rec_w[e,k]
//   t_k  = BETA*( (2/E)*sum_e m_e*rec_w[e,k] - (1/E)*sum_e rec_w[e,k]^2 )
//   yp   = softmax_k(t)
//   r*_d = sum_k yp_k * project_w[k,d]
//   loss_b = mean_d (r*_d - images[b,d])^2
//
// R7-R10 structure (unmeasured — four GPU-acquisition timeouts):
//  (1) reduce_t dispatch eliminated: rstar_fused computes its own 16 t_k's
//      from the col_stats partials (each k owned by exactly ONE block),
//      accumulates UNNORMALIZED u_d = sum_k exp(t_k) pw[k,d] and the scalar
//      denominator S via one atomicAdd/block. Normalization (1/S) deferred
//      to the loss kernel. Removes 1 dispatch + 128 redundant 2048-exp
//      denominator passes. 5 -> 4 dispatches.
//  (2) loss kernel wave-per-row: 64 lanes x 4 float4 per row, pure
//      __shfl_xor reduce. No LDS, no __syncthreads on the 32 MB (65% of our
//      traffic) stream. 2048 blocks x 4 waves.
//  (3) zero-init of u and S piggybacks on col_stats block (0,0) (stream-
//      ordered before rstar_fused) — no memset dispatches issued by us.
//      Re-zeroed every graph replay, so repeated launches are safe.
// ---------------------------------------------------------------------------

__device__ __forceinline__ float blk_reduce_sum(float v) {
    #pragma unroll
    for (int off = 32; off > 0; off >>= 1) v += __shfl_xor(v, off);
    __shared__ float red[4];
    __syncthreads();
    if ((threadIdx.x & 63) == 0) red[threadIdx.x >> 6] = v;
    __syncthreads();
    return (red[0] + red[1]) + (red[2] + red[3]);
}

// m[e] = mean_k rec_w[e,k]   (block per row e; 256 thr x 2 float4 = 2048)
__global__ __launch_bounds__(256) void row_mean(
    const float* __restrict__ w, float* __restrict__ m)
{
    size_t base = (size_t)blockIdx.x * Kk;
    const float4* p = (const float4*)(w + base);
    float4 a = p[threadIdx.x];
    float4 b = p[threadIdx.x + 256];
    float s = (a.x + a.y + a.z + a.w) + (b.x + b.y + b.z + b.w);
    s = blk_reduce_sum(s);
    if (threadIdx.x == 0) m[blockIdx.x] = s * (1.f / (float)Kk);
}

// Column partial stats over a 16-row chunk of rec_w (E,K):
//   tm_part[eb][k] = sum_e m[e]*w[e,k],  tsq_part[eb][k] = sum_e w[e,k]^2
// grid (2, 32) = 64 blocks; thread owns 4 k's (float4); 16 batched dwordx4
// loads up-front (ILP). Direct partial stores: no atomics, no memset.
// Block (0,0) additionally zeroes u (4 KB) and S — consumed by the NEXT
// dispatch (stream-ordered), so no hipMemsetAsync anywhere.
__global__ __launch_bounds__(256) void col_stats(
    const float* __restrict__ w, const float* __restrict__ m,
    float* __restrict__ tm_part, float* __restrict__ tsq_part,
    float* __restrict__ u, float* __restrict__ Ssum)
{
    const int k4 = blockIdx.x * 256 + threadIdx.x;   // float4 column index
    const int eb = blockIdx.y;
    const int e0 = eb * 16;
    const float4* wp = (const float4*)w;             // (E, K/4)
    float4 vs[16];
    #pragma unroll
    for (int j = 0; j < 16; j++)
        vs[j] = wp[(size_t)(e0 + j) * (Kk / 4) + k4];
    float4 sm = {0.f, 0.f, 0.f, 0.f}, sq = {0.f, 0.f, 0.f, 0.f};
    #pragma unroll
    for (int j = 0; j < 16; j++) {
        float mv = m[e0 + j];                        // wave-uniform scalar load
        sm.x += mv * vs[j].x; sm.y += mv * vs[j].y;
        sm.z += mv * vs[j].z; sm.w += mv * vs[j].w;
        sq.x += vs[j].x * vs[j].x; sq.y += vs[j].y * vs[j].y;
        sq.z += vs[j].z * vs[j].z; sq.w += vs[j].w * vs[j].w;
    }
    ((float4*)(tm_part  + (size_t)eb * Kk))[k4] = sm;
    ((float4*)(tsq_part + (size_t)eb * Kk))[k4] = sq;
    if (blockIdx.x == 0 && blockIdx.y == 0) {
        float4 z = {0.f, 0.f, 0.f, 0.f};
        ((float4*)u)[threadIdx.x] = z;               // 256 x 16B = 1024 floats
        if (threadIdx.x == 0) *Ssum = 0.f;
    }
}

// Fused reduce_t + softmax-numerator + rstar accumulation. Grid 128 blocks,
// each owns 16 k-rows of project_w. Prologue: reduce the 32 eb-partials for
// this block's 16 k's (each thread sums 2 eb's for one k; LDS tree finishes),
// t<16 computes t_k and exp(t_k) (|t|<1e-2 — no max-subtraction needed).
// One atomicAdd of the block's 16-exp partial into the global denominator S.
// Main body: u_d += sum_j exp(t_j) * pw[k0+j, d]  (unnormalized; /S deferred
// to loss). pw loads issued FIRST so HBM latency hides the prologue.
__global__ __launch_bounds__(256) void rstar_fused(
    const float* __restrict__ tm_part, const float* __restrict__ tsq_part,
    const float* __restrict__ pw, float* __restrict__ u,
    float* __restrict__ Ssum)
{
    __shared__ float sm_tm[256], sm_ts[256], sm_e[16];
    const int t = threadIdx.x;
    const int k0 = blockIdx.x * 16;

    // issue the 16 project_w row loads early (64 VGPRs of ILP)
    const float4* pwp = (const float4*)pw;           // (K, D/4 = 256)
    float4 vs[16];
    #pragma unroll
    for (int j = 0; j < 16; j++)
        vs[j] = pwp[(size_t)(k0 + j) * (Dd / 4) + t];

    // per-thread partial: k = k0 + (t&15), eb pair (2g, 2g+1), g = t>>4
    const int kl = t & 15, g = t >> 4;
    const int k = k0 + kl;
    float ptm = tm_part[(size_t)(2 * g) * Kk + k]
              + tm_part[(size_t)(2 * g + 1) * Kk + k];
    float pts = tsq_part[(size_t)(2 * g) * Kk + k]
              + tsq_part[(size_t)(2 * g + 1) * Kk + k];
    sm_tm[t] = ptm; sm_ts[t] = pts;
    __syncthreads();
    if (t < 16) {
        float tmv = 0.f, tsv = 0.f;
        #pragma unroll
        for (int gg = 0; gg < 16; gg++) {
            tmv += sm_tm[gg * 16 + t];
            tsv += sm_ts[gg * 16 + t];
        }
        float tk = BETA_F * ((2.f / (float)Ee) * tmv - tsv * (1.f / (float)Ee));
        sm_e[t] = __expf(tk);
    }
    __syncthreads();
    if (t == 0) {
        float s = 0.f;
        #pragma unroll
        for (int j = 0; j < 16; j++) s += sm_e[j];
        atomicAdd(Ssum, s);
    }
    float4 acc = {0.f, 0.f, 0.f, 0.f};
    #pragma unroll
    for (int j = 0; j < 16; j++) {
        float wv = sm_e[j];
        acc.x += wv * vs[j].x; acc.y += wv * vs[j].y;
        acc.z += wv * vs[j].z; acc.w += wv * vs[j].w;
    }
    int d = t * 4;
    atomicAdd(&u[d + 0], acc.x); atomicAdd(&u[d + 1], acc.y);
    atomicAdd(&u[d + 2], acc.z); atomicAdd(&u[d + 3], acc.w);
}

// loss[b] = (1/D) * sum_d (u[d]/S - img[b,d])^2
// Wave-per-row: 64 lanes x 4 float4 = 1024 floats = one row. Pure shuffle
// reduce — no LDS, no barriers on the 32 MB stream. Grid 2048 x 4 waves.
__global__ __launch_bounds__(256) void loss_wave(
    const float* __restrict__ img, const float* __restrict__ u,
    const float* __restrict__ Ssum, float* __restrict__ loss)
{
    const int lane = threadIdx.x & 63;
    const int row  = blockIdx.x * 4 + (threadIdx.x >> 6);
    const float inv = 1.f / (*Ssum);                 // wave-uniform scalar load
    const float4* xp = (const float4*)(img + (size_t)row * Dd);
    const float4* up = (const float4*)u;
    float s = 0.f;
    #pragma unroll
    for (int j = 0; j < 4; j++) {
        float4 x = xp[lane + 64 * j];
        float4 r = up[lane + 64 * j];                // L1/L2-hot 4 KB
        float dx = r.x * inv - x.x, dy = r.y * inv - x.y,
              dz = r.z * inv - x.z, dw = r.w * inv - x.w;
        s += dx * dx + dy * dy + dz * dz + dw * dw;
    }
    #pragma unroll
    for (int off = 32; off > 0; off >>= 1) s += __shfl_xor(s, off);
    if (lane == 0) loss[row] = s * (1.f / (float)Dd);
}

extern "C" void kernel_launch(void* const* d_in, const int* in_sizes, int n_in,
                              void* d_out, int out_size, void* d_ws, size_t ws_size,
                              hipStream_t stream) {
    const float* images    = (const float*)d_in[0];   // (B, D)
    const float* project_w = (const float*)d_in[1];   // (K, D)
    const float* rec_w     = (const float*)d_in[2];   // (E, K)
    float* loss_out = (float*)d_out;                  // (B,)

    // workspace: tm_part(32K) | tsq_part(32K) | u(D) | S(+pad) | m(E)
    float* tm_part  = (float*)d_ws;
    float* tsq_part = tm_part + 32 * Kk;
    float* u        = tsq_part + 32 * Kk;
    float* Ssum     = u + Dd;            // own 128B line (u ends at +1024)
    float* m        = Ssum + 64;

    row_mean<<<Ee, 256, 0, stream>>>(rec_w, m);
    col_stats<<<dim3(2, 32), 256, 0, stream>>>(rec_w, m, tm_part, tsq_part, u, Ssum);
    rstar_fused<<<Kk / 16, 256, 0, stream>>>(tm_part, tsq_part, project_w, u, Ssum);
    loss_wave<<<Bn / 4, 256, 0, stream>>>(images, u, Ssum, loss_out);
}

// Round 5
// 99.484 us; speedup vs baseline: 1.0000x; 1.0000x over previous
//
#include <hip/hip_runtime.h>

#define BETA_F 0.001f
constexpr int Bn = 8192, Dd = 1024, Kk = 2048, Ee = 512;

// ---------------------------------------------------------------------------
// Collapsed pipeline (validated R3-R6 + R11 measured 99.49us, absmax 0.0):
//   m_e  = mean_k rec_w[e,k]
//   t_k  = BETA*( (2/E)*sum_e m_e*rec_w[e,k] - (1/E)*sum_e rec_w[e,k]^2 )
//   yp   = softmax_k(t)
//   r*_d = sum_k yp_k * project_w[k,d]
//   loss_b = mean_d (r*_d - images[b,d])^2
//
// R11 post-mortem: 99.49us = ~88us harness poison fills (2 x 268MB @ 6.2TB/s,
// untouchable) + ~11.5us ours. Deferred-normalization fusion + wave-per-row
// loss verified good (our portion 15 -> 11.5us).
// R12 change: row_mean fused INTO col_stats. Block eb @ 512 threads loads its
// 16 rec_w rows IN FULL (512 x float4 = 2048 = K), so the row means it needs
// are in-block reducible — no cross-block dep, no separate dispatch, no
// second 4MB read of rec_w. 4 -> 3 dispatches, 48 -> 44MB our traffic.
// Structural ceiling ~= 88 + 7 + dispatch tails ~= 97us.
// ---------------------------------------------------------------------------

// Fused row-mean + column partial stats over a 16-row chunk of rec_w (E,K):
//   m_e       = mean_k w[e,k]            (in-block, 8-wave shuffle+LDS tree)
//   tm_part[eb][k] = sum_{e in chunk} m_e*w[e,k]
//   tsq_part[eb][k] = sum_{e in chunk} w[e,k]^2
// grid 32 blocks x 512 threads; thread owns 4 k's (float4) of all 16 rows;
// 16 batched dwordx4 loads up-front (ILP). Direct partial stores.
// Block 0 additionally zeroes u (4 KB) and S — consumed by the NEXT dispatch
// (stream-ordered, re-zeroed every graph replay), so no hipMemsetAsync.
__global__ __launch_bounds__(512) void stats_fused(
    const float* __restrict__ w,
    float* __restrict__ tm_part, float* __restrict__ tsq_part,
    float* __restrict__ u, float* __restrict__ Ssum)
{
    __shared__ float red[8][16];   // per-wave row sums
    __shared__ float sm_m[16];     // the 16 row means
    const int t = threadIdx.x;
    const int lane = t & 63, wv = t >> 6;
    const int eb = blockIdx.x;
    const int e0 = eb * 16;
    const float4* wp = (const float4*)w;             // (E, K/4 = 512)

    float4 vs[16];
    #pragma unroll
    for (int j = 0; j < 16; j++)
        vs[j] = wp[(size_t)(e0 + j) * (Kk / 4) + t];

    // 16 row sums: per-wave shuffle reduce, then 8-wave LDS combine
    #pragma unroll
    for (int j = 0; j < 16; j++) {
        float s = (vs[j].x + vs[j].y) + (vs[j].z + vs[j].w);
        #pragma unroll
        for (int off = 32; off > 0; off >>= 1) s += __shfl_xor(s, off);
        if (lane == 0) red[wv][j] = s;
    }
    __syncthreads();
    if (t < 16) {
        float s = 0.f;
        #pragma unroll
        for (int g = 0; g < 8; g++) s += red[g][t];
        sm_m[t] = s * (1.f / (float)Kk);
    }
    __syncthreads();

    float4 sm = {0.f, 0.f, 0.f, 0.f}, sq = {0.f, 0.f, 0.f, 0.f};
    #pragma unroll
    for (int j = 0; j < 16; j++) {
        float mv = sm_m[j];
        sm.x += mv * vs[j].x; sm.y += mv * vs[j].y;
        sm.z += mv * vs[j].z; sm.w += mv * vs[j].w;
        sq.x += vs[j].x * vs[j].x; sq.y += vs[j].y * vs[j].y;
        sq.z += vs[j].z * vs[j].z; sq.w += vs[j].w * vs[j].w;
    }
    ((float4*)(tm_part  + (size_t)eb * Kk))[t] = sm;
    ((float4*)(tsq_part + (size_t)eb * Kk))[t] = sq;

    if (eb == 0) {
        if (t < 256) {
            float4 z = {0.f, 0.f, 0.f, 0.f};
            ((float4*)u)[t] = z;                     // 256 x 16B = 1024 floats
        }
        if (t == 0) *Ssum = 0.f;
    }
}

// Fused reduce_t + softmax-numerator + rstar accumulation. Grid 128 blocks,
// each owns 16 k-rows of project_w. Prologue: reduce the 32 eb-partials for
// this block's 16 k's (each thread sums 2 eb's for one k; LDS tree finishes),
// t<16 computes t_k and exp(t_k) (|t|<1e-2 — no max-subtraction needed).
// One atomicAdd of the block's 16-exp partial into the global denominator S.
// Main body: u_d += sum_j exp(t_j) * pw[k0+j, d]  (unnormalized; /S deferred
// to loss). pw loads issued FIRST so HBM latency hides the prologue.
__global__ __launch_bounds__(256) void rstar_fused(
    const float* __restrict__ tm_part, const float* __restrict__ tsq_part,
    const float* __restrict__ pw, float* __restrict__ u,
    float* __restrict__ Ssum)
{
    __shared__ float sm_tm[256], sm_ts[256], sm_e[16];
    const int t = threadIdx.x;
    const int k0 = blockIdx.x * 16;

    // issue the 16 project_w row loads early (64 VGPRs of ILP)
    const float4* pwp = (const float4*)pw;           // (K, D/4 = 256)
    float4 vs[16];
    #pragma unroll
    for (int j = 0; j < 16; j++)
        vs[j] = pwp[(size_t)(k0 + j) * (Dd / 4) + t];

    // per-thread partial: k = k0 + (t&15), eb pair (2g, 2g+1), g = t>>4
    const int kl = t & 15, g = t >> 4;
    const int k = k0 + kl;
    float ptm = tm_part[(size_t)(2 * g) * Kk + k]
              + tm_part[(size_t)(2 * g + 1) * Kk + k];
    float pts = tsq_part[(size_t)(2 * g) * Kk + k]
              + tsq_part[(size_t)(2 * g + 1) * Kk + k];
    sm_tm[t] = ptm; sm_ts[t] = pts;
    __syncthreads();
    if (t < 16) {
        float tmv = 0.f, tsv = 0.f;
        #pragma unroll
        for (int gg = 0; gg < 16; gg++) {
            tmv += sm_tm[gg * 16 + t];
            tsv += sm_ts[gg * 16 + t];
        }
        float tk = BETA_F * ((2.f / (float)Ee) * tmv - tsv * (1.f / (float)Ee));
        sm_e[t] = __expf(tk);
    }
    __syncthreads();
    if (t == 0) {
        float s = 0.f;
        #pragma unroll
        for (int j = 0; j < 16; j++) s += sm_e[j];
        atomicAdd(Ssum, s);
    }
    float4 acc = {0.f, 0.f, 0.f, 0.f};
    #pragma unroll
    for (int j = 0; j < 16; j++) {
        float wv = sm_e[j];
        acc.x += wv * vs[j].x; acc.y += wv * vs[j].y;
        acc.z += wv * vs[j].z; acc.w += wv * vs[j].w;
    }
    int d = t * 4;
    atomicAdd(&u[d + 0], acc.x); atomicAdd(&u[d + 1], acc.y);
    atomicAdd(&u[d + 2], acc.z); atomicAdd(&u[d + 3], acc.w);
}

// loss[b] = (1/D) * sum_d (u[d]/S - img[b,d])^2
// Wave-per-row: 64 lanes x 4 float4 = 1024 floats = one row. Pure shuffle
// reduce — no LDS, no barriers on the 32 MB stream. Grid 2048 x 4 waves.
__global__ __launch_bounds__(256) void loss_wave(
    const float* __restrict__ img, const float* __restrict__ u,
    const float* __restrict__ Ssum, float* __restrict__ loss)
{
    const int lane = threadIdx.x & 63;
    const int row  = blockIdx.x * 4 + (threadIdx.x >> 6);
    const float inv = 1.f / (*Ssum);                 // wave-uniform scalar load
    const float4* xp = (const float4*)(img + (size_t)row * Dd);
    const float4* up = (const float4*)u;
    float s = 0.f;
    #pragma unroll
    for (int j = 0; j < 4; j++) {
        float4 x = xp[lane + 64 * j];
        float4 r = up[lane + 64 * j];                // L1/L2-hot 4 KB
        float dx = r.x * inv - x.x, dy = r.y * inv - x.y,
              dz = r.z * inv - x.z, dw = r.w * inv - x.w;
        s += dx * dx + dy * dy + dz * dz + dw * dw;
    }
    #pragma unroll
    for (int off = 32; off > 0; off >>= 1) s += __shfl_xor(s, off);
    if (lane == 0) loss[row] = s * (1.f / (float)Dd);
}

extern "C" void kernel_launch(void* const* d_in, const int* in_sizes, int n_in,
                              void* d_out, int out_size, void* d_ws, size_t ws_size,
                              hipStream_t stream) {
    const float* images    = (const float*)d_in[0];   // (B, D)
    const float* project_w = (const float*)d_in[1];   // (K, D)
    const float* rec_w     = (const float*)d_in[2];   // (E, K)
    float* loss_out = (float*)d_out;                  // (B,)

    // workspace: tm_part(32K) | tsq_part(32K) | u(D) | S(+pad)
    float* tm_part  = (float*)d_ws;
    float* tsq_part = tm_part + 32 * Kk;
    float* u        = tsq_part + 32 * Kk;
    float* Ssum     = u + Dd;            // own 128B line (u ends at +1024)

    stats_fused<<<32, 512, 0, stream>>>(rec_w, tm_part, tsq_part, u, Ssum);
    rstar_fused<<<Kk / 16, 256, 0, stream>>>(tm_part, tsq_part, project_w, u, Ssum);
    loss_wave<<<Bn / 4, 256, 0, stream>>>(images, u, Ssum, loss_out);
}

// Round 6
// 97.215 us; speedup vs baseline: 1.0234x; 1.0233x over previous
//
#include <hip/hip_runtime.h>

#define BETA_F 0.001f
constexpr int Bn = 8192, Dd = 1024, Kk = 2048, Ee = 512;

// ---------------------------------------------------------------------------
// Collapsed pipeline (validated through R12, absmax 0.0 every round):
//   m_e  = mean_k rec_w[e,k]
//   t_k  = BETA*( (2/E)*sum_e m_e*rec_w[e,k] - (1/E)*sum_e rec_w[e,k]^2 )
//   yp   = softmax_k(t);  r*_d = sum_k yp_k * pw[k,d]
//   loss_b = mean_d (r*_d - images[b,d])^2
//
// Measured: R11 99.49us, R12 99.48us (identical). R12 post-mortem: fills got
// FASTER (43-45.5 -> 41.3-42.3us) while total held => our chain got slower.
// Cause: stats_fused at 32 blocks = 12.5% of CUs = ~0.8 TB/s BW share, so the
// 4MB rec_w read cost ~4-5us, cancelling the removed row_mean dispatch.
// R13: same fusion, 4-row chunks x 128 blocks (50% CU coverage, ~1.3us for
// 4MB). Partials deepen to 128 ebs (2MB round-trip, +0.6us) - net ~-3us.
// rstar prologue: each thread sums 8 ebs (16 groups x 8 = 128).
// ---------------------------------------------------------------------------

// Fused row-mean + column partial stats over a 4-row chunk of rec_w (E,K):
// grid 128 x 512 thr; thread owns one float4 column-group of all 4 rows.
// In-block row means (512 thr = 2048 floats = full row). Direct partial
// stores, no atomics. Block 0 zeroes u + S for the NEXT dispatch (stream-
// ordered, re-zeroed every replay) - no hipMemsetAsync anywhere.
__global__ __launch_bounds__(512) void stats_fused(
    const float* __restrict__ w,
    float* __restrict__ tm_part, float* __restrict__ tsq_part,
    float* __restrict__ u, float* __restrict__ Ssum)
{
    __shared__ float red[8][4];    // per-wave row sums
    __shared__ float sm_m[4];      // the 4 row means
    const int t = threadIdx.x;
    const int lane = t & 63, wv = t >> 6;
    const int eb = blockIdx.x;
    const int e0 = eb * 4;
    const float4* wp = (const float4*)w;             // (E, K/4 = 512)

    float4 vs[4];
    #pragma unroll
    for (int j = 0; j < 4; j++)
        vs[j] = wp[(size_t)(e0 + j) * (Kk / 4) + t];

    #pragma unroll
    for (int j = 0; j < 4; j++) {
        float s = (vs[j].x + vs[j].y) + (vs[j].z + vs[j].w);
        #pragma unroll
        for (int off = 32; off > 0; off >>= 1) s += __shfl_xor(s, off);
        if (lane == 0) red[wv][j] = s;
    }
    __syncthreads();
    if (t < 4) {
        float s = 0.f;
        #pragma unroll
        for (int g = 0; g < 8; g++) s += red[g][t];
        sm_m[t] = s * (1.f / (float)Kk);
    }
    __syncthreads();

    float4 sm = {0.f, 0.f, 0.f, 0.f}, sq = {0.f, 0.f, 0.f, 0.f};
    #pragma unroll
    for (int j = 0; j < 4; j++) {
        float mv = sm_m[j];
        sm.x += mv * vs[j].x; sm.y += mv * vs[j].y;
        sm.z += mv * vs[j].z; sm.w += mv * vs[j].w;
        sq.x += vs[j].x * vs[j].x; sq.y += vs[j].y * vs[j].y;
        sq.z += vs[j].z * vs[j].z; sq.w += vs[j].w * vs[j].w;
    }
    ((float4*)(tm_part  + (size_t)eb * Kk))[t] = sm;
    ((float4*)(tsq_part + (size_t)eb * Kk))[t] = sq;

    if (eb == 0) {
        if (t < 256) {
            float4 z = {0.f, 0.f, 0.f, 0.f};
            ((float4*)u)[t] = z;                     // 1024 floats
        }
        if (t == 0) *Ssum = 0.f;
    }
}

// Fused reduce_t + softmax-numerator + rstar accumulation. Grid 128 blocks,
// each owns 16 k-rows of project_w. Prologue: reduce the 128 eb-partials for
// this block's 16 k's (thread (kl,g) sums ebs 8g..8g+7; LDS tree finishes),
// t<16 computes t_k and exp(t_k) (|t|<1e-2 - no max-subtraction needed).
// One atomicAdd of the block's 16-exp partial into the global denominator S.
// Main body: u_d += sum_j exp(t_j) * pw[k0+j, d]  (unnormalized; /S deferred
// to loss). pw loads issued FIRST so HBM latency hides the prologue.
__global__ __launch_bounds__(256) void rstar_fused(
    const float* __restrict__ tm_part, const float* __restrict__ tsq_part,
    const float* __restrict__ pw, float* __restrict__ u,
    float* __restrict__ Ssum)
{
    __shared__ float sm_tm[256], sm_ts[256], sm_e[16];
    const int t = threadIdx.x;
    const int k0 = blockIdx.x * 16;

    // issue the 16 project_w row loads early (64 VGPRs of ILP)
    const float4* pwp = (const float4*)pw;           // (K, D/4 = 256)
    float4 vs[16];
    #pragma unroll
    for (int j = 0; j < 16; j++)
        vs[j] = pwp[(size_t)(k0 + j) * (Dd / 4) + t];

    // per-thread partial: k = k0 + (t&15), ebs [8g, 8g+8), g = t>>4
    const int kl = t & 15, g = t >> 4;
    const int k = k0 + kl;
    float ptm = 0.f, pts = 0.f;
    #pragma unroll
    for (int j = 0; j < 8; j++) {
        ptm += tm_part[(size_t)(8 * g + j) * Kk + k];
        pts += tsq_part[(size_t)(8 * g + j) * Kk + k];
    }
    sm_tm[t] = ptm; sm_ts[t] = pts;
    __syncthreads();
    if (t < 16) {
        float tmv = 0.f, tsv = 0.f;
        #pragma unroll
        for (int gg = 0; gg < 16; gg++) {
            tmv += sm_tm[gg * 16 + t];
            tsv += sm_ts[gg * 16 + t];
        }
        float tk = BETA_F * ((2.f / (float)Ee) * tmv - tsv * (1.f / (float)Ee));
        sm_e[t] = __expf(tk);
    }
    __syncthreads();
    if (t == 0) {
        float s = 0.f;
        #pragma unroll
        for (int j = 0; j < 16; j++) s += sm_e[j];
        atomicAdd(Ssum, s);
    }
    float4 acc = {0.f, 0.f, 0.f, 0.f};
    #pragma unroll
    for (int j = 0; j < 16; j++) {
        float wv = sm_e[j];
        acc.x += wv * vs[j].x; acc.y += wv * vs[j].y;
        acc.z += wv * vs[j].z; acc.w += wv * vs[j].w;
    }
    int d = t * 4;
    atomicAdd(&u[d + 0], acc.x); atomicAdd(&u[d + 1], acc.y);
    atomicAdd(&u[d + 2], acc.z); atomicAdd(&u[d + 3], acc.w);
}

// loss[b] = (1/D) * sum_d (u[d]/S - img[b,d])^2
// Wave-per-row: 64 lanes x 4 float4 = 1024 floats = one row. Pure shuffle
// reduce - no LDS, no barriers on the 32 MB stream. Grid 2048 x 4 waves.
__global__ __launch_bounds__(256) void loss_wave(
    const float* __restrict__ img, const float* __restrict__ u,
    const float* __restrict__ Ssum, float* __restrict__ loss)
{
    const int lane = threadIdx.x & 63;
    const int row  = blockIdx.x * 4 + (threadIdx.x >> 6);
    const float inv = 1.f / (*Ssum);                 // wave-uniform scalar load
    const float4* xp = (const float4*)(img + (size_t)row * Dd);
    const float4* up = (const float4*)u;
    float s = 0.f;
    #pragma unroll
    for (int j = 0; j < 4; j++) {
        float4 x = xp[lane + 64 * j];
        float4 r = up[lane + 64 * j];                // L1/L2-hot 4 KB
        float dx = r.x * inv - x.x, dy = r.y * inv - x.y,
              dz = r.z * inv - x.z, dw = r.w * inv - x.w;
        s += dx * dx + dy * dy + dz * dz + dw * dw;
    }
    #pragma unroll
    for (int off = 32; off > 0; off >>= 1) s += __shfl_xor(s, off);
    if (lane == 0) loss[row] = s * (1.f / (float)Dd);
}

extern "C" void kernel_launch(void* const* d_in, const int* in_sizes, int n_in,
                              void* d_out, int out_size, void* d_ws, size_t ws_size,
                              hipStream_t stream) {
    const float* images    = (const float*)d_in[0];   // (B, D)
    const float* project_w = (const float*)d_in[1];   // (K, D)
    const float* rec_w     = (const float*)d_in[2];   // (E, K)
    float* loss_out = (float*)d_out;                  // (B,)

    // workspace: tm_part(128K) | tsq_part(128K) | u(D) | S(+pad)
    float* tm_part  = (float*)d_ws;
    float* tsq_part = tm_part + 128 * Kk;
    float* u        = tsq_part + 128 * Kk;
    float* Ssum     = u + Dd;            // own 128B line (u ends at +1024)

    stats_fused<<<128, 512, 0, stream>>>(rec_w, tm_part, tsq_part, u, Ssum);
    rstar_fused<<<Kk / 16, 256, 0, stream>>>(tm_part, tsq_part, project_w, u, Ssum);
    loss_wave<<<Bn / 4, 256, 0, stream>>>(images, u, Ssum, loss_out);
}